// Round 1
// 115.765 us; speedup vs baseline: 1.0531x; 1.0531x over previous
//
#include <hip/hip_runtime.h>
#include <hip/hip_bf16.h>

// ConvDeepSet round 7: occupancy + VALU-cut attack.
//  - 512-thread blocks (8 waves), 16 m-rows per wave -> 4096 waves total
//    = 4 waves/SIMD (was 2). Grid stays 512 (2 blocks/CU).
//  - exp argument via fma: -(x-y)^2 = (2x*y - x^2) - y^2. Prep writes
//    sxa = 2*sx and sxb = -sx^2 tables; inner loop is v_pk_fma + v_exp.
//    The row-constant exp2(-y^2) folds into the epilogue (V/dens ratio is
//    scale-invariant; only dens and the projection scale need it).
//  - B-stream staging unchanged: async global_load_lds 16B, double-buffered
//    16KB slabs, 16 chunks/period now spread over 8 waves (2 each).

#define N_CTX 2048
#define BATCH 16
#define M_TGT 4096
#define COUT  64
#define RDIM  128

#define WS_CO_BYTES (N_CTX * BATCH * COUT * 2)          // 4 MB
#define WS_SXA_OFF  WS_CO_BYTES                         // 128 KB fp32 (2*sx)
#define WS_SXB_OFF  (WS_SXA_OFF + N_CTX * BATCH * 4)    // 128 KB fp32 (-sx^2)
#define WS_WT_OFF   (WS_SXB_OFF + N_CTX * BATCH * 4)    // 16 KB bf16

#define SSCALE 0.8493222f   // sqrt(0.5 * log2(e))

typedef __attribute__((ext_vector_type(8)))  short        bf16x8;
typedef __attribute__((ext_vector_type(4)))  float        floatx4;
typedef __attribute__((ext_vector_type(4)))  unsigned int uint4v;

#if __has_builtin(__builtin_amdgcn_exp2f)
#define EXP2F __builtin_amdgcn_exp2f
#else
#define EXP2F exp2f
#endif

static __device__ __forceinline__ unsigned int pack_bf16(float lo, float hi) {
    __hip_bfloat162 h = __float22bfloat162_rn(make_float2(lo, hi));
    return *reinterpret_cast<unsigned int*>(&h);
}
static __device__ __forceinline__ unsigned short f2bf(float f) {
    __hip_bfloat16 h = __float2bfloat16(f);
    return *reinterpret_cast<unsigned short*>(&h);
}

__global__ __launch_bounds__(256)
void convdeepset_prep(const float* __restrict__ ci, const float* __restrict__ co,
                      const float* __restrict__ ls, const float* __restrict__ W,
                      unsigned char* __restrict__ ws)
{
    unsigned short* cow = (unsigned short*)ws;
    float*          sxa = (float*)(ws + WS_SXA_OFF);
    float*          sxb = (float*)(ws + WS_SXB_OFF);
    unsigned short* wt  = (unsigned short*)(ws + WS_WT_OFF);
    const int blk = blockIdx.x, tid = threadIdx.x;

    if (blk < 1024) {
        // group = (bb, nblk of 8 n); lane = c. Reads coalesced (256B/row),
        // writes fully coalesced dwordx4.
        const int g    = blk * 4 + (tid >> 6);
        const int bb   = g & 15;
        const int nblk = g >> 4;           // 0..255
        const int c    = tid & 63;
        const float* rp = co + ((size_t)nblk * 8 * BATCH + bb) * COUT + c;
        unsigned int u[4];
#pragma unroll
        for (int j = 0; j < 4; ++j) {
            const float f0 = rp[(size_t)(2 * j)     * BATCH * COUT];
            const float f1 = rp[(size_t)(2 * j + 1) * BATCH * COUT];
            u[j] = pack_bf16(f0, f1);
        }
        *(uint4v*)&cow[(size_t)bb * 131072 + nblk * 512 + c * 8] = *(uint4v*)u;
    } else if (blk < 1152) {
        const int f = (blk - 1024) * 256 + tid;   // 0..32767
        const int n = f & 2047, bb = f >> 11;
        const float s = SSCALE / ls[0];
        const float v = s * ci[(size_t)n * BATCH + bb];
        sxa[bb * 2048 + n] = v + v;     // 2*sx
        sxb[bb * 2048 + n] = -v * v;    // -sx^2
    } else {
        for (int f = tid; f < 8192; f += 256) {
            const int cp = f & 7, r = (f >> 3) & 127, ch = f >> 10;
            wt[ch * 1024 + r * 8 + cp] = f2bf(W[r * 65 + 1 + ch * 8 + cp]);
        }
    }
}

__global__ __launch_bounds__(512, 4)
void convdeepset_main(const float* __restrict__ ti, const float* __restrict__ ls,
                      const float* __restrict__ W,  const float* __restrict__ bias,
                      const unsigned char* __restrict__ ws, float* __restrict__ out)
{
    __shared__ float sxa[N_CTX];                  //  8 KB: 2*sx
    __shared__ float sxb[N_CTX];                  //  8 KB: -sx^2
    __shared__ unsigned short slab[2][8192];      // 32 KB double-buffered B stream
    __shared__ unsigned short vstage[8][1024];    // 16 KB V staging, A-frag layout
    __shared__ float w0l[RDIM], biasl[RDIM];      //  1 KB
    __shared__ float syt[128];                    //  0.5 KB: y^2 per (wave,row)
    // 65.5 KB -> 2 blocks/CU x 8 waves = 16 waves/CU = 4 waves/SIMD

    const int tid  = threadIdx.x;
    const int lane = tid & 63;
    const int wv   = tid >> 6;        // 0..7
    const int g2   = lane >> 4;       // MFMA k-group 0..3
    const int l15  = lane & 15;

    // XCD swizzle: 2 batches pinned per XCD (round-robin dispatch by blk&7)
    const int xcd = blockIdx.x & 7;
    const int i   = blockIdx.x >> 3;  // 0..63
    const int b   = xcd * 2 + (i & 1);
    const int mt  = i >> 1;           // 0..31
    const int m0  = mt * 128 + wv * 16;

    // stage x tables (coalesced float4) + epilogue tables
    const float4* sag = (const float4*)(ws + WS_SXA_OFF) + b * (N_CTX / 4);
    const float4* sbg = (const float4*)(ws + WS_SXB_OFF) + b * (N_CTX / 4);
    ((float4*)sxa)[tid] = sag[tid];
    ((float4*)sxb)[tid] = sbg[tid];
    if (tid < RDIM) { w0l[tid] = W[tid * 65]; biasl[tid] = bias[tid]; }

    const float s  = SSCALE / ls[0];
    const float sy = s * ti[(size_t)(m0 + l15) * BATCH + b];
    if (g2 == 0) syt[wv * 16 + l15] = sy * sy;

    const unsigned short* cowb = (const unsigned short*)ws + (size_t)b * 131072;

    // async staging: period p = 16 contiguous 1KB chunks; each wave DMAs 2
    typedef const __attribute__((address_space(1))) unsigned int* gp_t;
    typedef __attribute__((address_space(3))) unsigned int* lp_t;
    auto stage = [&](int period, int buf) {
        const unsigned short* gsrc = cowb + (size_t)period * 8192;
#pragma unroll
        for (int j = 0; j < 2; ++j) {
            const int ch = wv * 2 + j;
            __builtin_amdgcn_global_load_lds((gp_t)(gsrc + ch * 512 + lane * 8),
                                             (lp_t)(&slab[buf][ch * 512]),
                                             16, 0, 0);
        }
    };

    const short onebf = (short)0x3F80;
    bf16x8 ones;
#pragma unroll
    for (int j = 0; j < 8; ++j) ones[j] = onebf;

    floatx4 acc[4], accd;
#pragma unroll
    for (int q = 0; q < 4; ++q)
#pragma unroll
        for (int e = 0; e < 4; ++e) acc[q][e] = 0.0f;
#pragma unroll
    for (int e = 0; e < 4; ++e) accd[e] = 0.0f;

    stage(0, 0);
    __syncthreads();   // drains DMA (vmcnt) + sxa/sxb/syt visible

    for (int p = 0; p < 16; ++p) {
        if (p + 1 < 16) stage(p + 1, (p + 1) & 1);    // async into other slab
        const unsigned short* sb = &slab[p & 1][0];
#pragma unroll
        for (int k2 = 0; k2 < 4; ++k2) {
            const int ks = p * 4 + k2;
            const float* xap = &sxa[ks * 32 + g2 * 8];
            const float* xbp = &sxb[ks * 32 + g2 * 8];
            // arg = 2*sx*sy - sx^2   (the -sy^2 term folds into the epilogue)
            const floatx4 arg0 = (*(const floatx4*)xap)       * sy + (*(const floatx4*)xbp);
            const floatx4 arg1 = (*(const floatx4*)(xap + 4)) * sy + (*(const floatx4*)(xbp + 4));
            const unsigned short* bp = sb + (k2 * 4 + g2) * 512 + l15 * 8;
            const bf16x8 c0 = *(const bf16x8*)(bp);
            const bf16x8 c1 = *(const bf16x8*)(bp + 128);
            const bf16x8 c2 = *(const bf16x8*)(bp + 256);
            const bf16x8 c3 = *(const bf16x8*)(bp + 384);
            float kv[8];
            kv[0] = EXP2F(arg0.x); kv[1] = EXP2F(arg0.y);
            kv[2] = EXP2F(arg0.z); kv[3] = EXP2F(arg0.w);
            kv[4] = EXP2F(arg1.x); kv[5] = EXP2F(arg1.y);
            kv[6] = EXP2F(arg1.z); kv[7] = EXP2F(arg1.w);
            uint4v aw;
#pragma unroll
            for (int q = 0; q < 4; ++q)
                aw[q] = pack_bf16(kv[2 * q], kv[2 * q + 1]);
            const bf16x8 av = __builtin_bit_cast(bf16x8, aw);
            acc[0] = __builtin_amdgcn_mfma_f32_16x16x32_bf16(av, c0, acc[0], 0, 0, 0);
            acc[1] = __builtin_amdgcn_mfma_f32_16x16x32_bf16(av, c1, acc[1], 0, 0, 0);
            acc[2] = __builtin_amdgcn_mfma_f32_16x16x32_bf16(av, c2, acc[2], 0, 0, 0);
            acc[3] = __builtin_amdgcn_mfma_f32_16x16x32_bf16(av, c3, acc[3], 0, 0, 0);
            accd   = __builtin_amdgcn_mfma_f32_16x16x32_bf16(av, ones, accd, 0, 0, 0);
        }
        __syncthreads();   // slab handoff (drains next-slab DMA too)
    }

    // ---- epilogue: stage V, project, scale by exp2(-y^2), store ----
    const unsigned short* wtg = (const unsigned short*)(ws + WS_WT_OFF);

    // per-row factors: e = exp2(-y^2); dens_true = accd*e; scale = e/(dens+eps)
    float dt[4], ff[4];
#pragma unroll
    for (int reg = 0; reg < 4; ++reg) {
        const int m  = (lane >> 4) * 4 + reg;    // C/D map: row=(lane>>4)*4+reg
        const float e = EXP2F(-syt[wv * 16 + m]);
        dt[reg] = accd[reg] * e;
        ff[reg] = e / (dt[reg] + 1e-8f);
    }

    unsigned short* vs = vstage[wv];
#pragma unroll
    for (int reg = 0; reg < 4; ++reg) {
        const int m = (lane >> 4) * 4 + reg;
#pragma unroll
        for (int q = 0; q < 4; ++q) {
            const int c = q * 16 + l15;
            vs[(c >> 3) * 128 + m * 8 + (c & 7)] = f2bf(acc[q][reg]);
        }
    }
    // projection: D[16m][128r] = V @ Wt, same-wave LDS (no barrier)
    floatx4 pacc[8];
#pragma unroll
    for (int rt = 0; rt < 8; ++rt)
#pragma unroll
        for (int e = 0; e < 4; ++e) pacc[rt][e] = 0.0f;
#pragma unroll
    for (int s2 = 0; s2 < 2; ++s2) {
        const int ch = s2 * 4 + g2;
        const bf16x8 avp = *(const bf16x8*)&vs[ch * 128 + l15 * 8];
#pragma unroll
        for (int rt = 0; rt < 8; ++rt) {
            const bf16x8 bvp = *(const bf16x8*)&wtg[ch * 1024 + (rt * 16 + l15) * 8];
            pacc[rt] = __builtin_amdgcn_mfma_f32_16x16x32_bf16(avp, bvp, pacc[rt], 0, 0, 0);
        }
    }
    // out = pacc*e/dens + dens*W0 + bias
#pragma unroll
    for (int rt = 0; rt < 8; ++rt) {
        const int r = rt * 16 + l15;
        const float w0v = w0l[r];
        const float bv  = biasl[r];
#pragma unroll
        for (int reg = 0; reg < 4; ++reg) {
            const int m = (lane >> 4) * 4 + reg;
            out[((size_t)(m0 + m) * BATCH + b) * RDIM + r]
                = pacc[rt][reg] * ff[reg] + dt[reg] * w0v + bv;
        }
    }
}

extern "C" void kernel_launch(void* const* d_in, const int* in_sizes, int n_in,
                              void* d_out, int out_size, void* d_ws, size_t ws_size,
                              hipStream_t stream) {
    const float* ci   = (const float*)d_in[0];  // context_in  (N,B,1)
    const float* co   = (const float*)d_in[1];  // context_out (N,B,64)
    const float* ti   = (const float*)d_in[2];  // target_in   (M,B,1)
    const float* ls   = (const float*)d_in[3];  // lengthscale (1,)
    const float* W    = (const float*)d_in[4];  // (128,65)
    const float* bias = (const float*)d_in[5];  // (128,)
    float* o = (float*)d_out;                   // (M,B,128)
    (void)in_sizes; (void)n_in; (void)out_size; (void)ws_size;

    convdeepset_prep<<<1153, 256, 0, stream>>>(ci, co, ls, W, (unsigned char*)d_ws);
    convdeepset_main<<<512, 512, 0, stream>>>(
        ti, ls, W, bias, (const unsigned char*)d_ws, o);
}